// Round 10
// baseline (206.746 us; speedup 1.0000x reference)
//
#include <hip/hip_runtime.h>
#include <hip/hip_bf16.h>

// Shapes (fixed by reference): B=8, N=1024, Din=256, H=4, Dh=128, Do=64
#define BSZ 8
#define NN 1024
#define DIN 256
#define NH 4
#define DH 128
#define DOUT 64
#define RTOT (BSZ*NN)          // 8192 rows total
#define FCAT (NH*DH)           // 512
#define ALPHA 0.2f

typedef unsigned short ushortT;
typedef __attribute__((ext_vector_type(8))) short bf16x8;
typedef __attribute__((ext_vector_type(4))) float f32x4;

static __device__ __forceinline__ ushortT f2bf(float f) {
    __hip_bfloat16 h = __float2bfloat16(f);
    return *reinterpret_cast<ushortT*>(&h);
}
static __device__ __forceinline__ float bfu2f(ushortT u) {
    return __uint_as_float(((unsigned)u) << 16);
}
static __device__ __forceinline__ void split2(float v, ushortT& hi, ushortT& lo) {
    hi = f2bf(v);
    lo = f2bf(v - bfu2f(hi));
}
// async global->LDS, 16B per lane; LDS dest = base(wave-uniform) + lane*16
static __device__ __forceinline__ void gload16(const ushortT* g, ushortT* l) {
    __builtin_amdgcn_global_load_lds(
        (const __attribute__((address_space(1))) unsigned int*)(const void*)g,
        (__attribute__((address_space(3))) unsigned int*)(void*)l, 16, 0, 0);
}

// ============ k_prepw: weight transforms only (bf16 hi/lo, k-contig) ============
__global__ __launch_bounds__(256) void k_prepw(const float* __restrict__ W,
                                               const float* __restrict__ Wout,
                                               ushortT* __restrict__ WbTh, ushortT* __restrict__ WbTl,
                                               ushortT* __restrict__ WoTh, ushortT* __restrict__ WoTl) {
    const int g2 = blockIdx.x * 256 + threadIdx.x;
    if (g2 < NH * DH * DIN) {           // 131072
        const int h = g2 >> 15, f = (g2 >> 8) & 127, k = g2 & 255;
        const int kt = k >> 6, k64 = k & 63;
        const float v = W[(size_t)h * DIN * DH + (size_t)k * DH + f];
        ushortT hi, lo; split2(v, hi, lo);
        const int idx = ((h * 4 + kt) * 128 + f) * 64 + k64;
        WbTh[idx] = hi; WbTl[idx] = lo;
    } else {
        const int g3 = g2 - NH * DH * DIN;   // < 32768
        const int f = g3 >> 9, k = g3 & 511;
        const float v = Wout[(size_t)k * DOUT + f];
        ushortT hi, lo; split2(v, hi, lo);
        WoTh[g3] = hi; WoTl[g3] = lo;
    }
}

// ============ k_main: blocks 0..255 = wh1 MFMA GEMM; blocks 256..767 = adj bit-pack ============
__global__ __launch_bounds__(512) void k_main(const float* __restrict__ x,
                                              const float* __restrict__ ah_,
                                              const ushortT* __restrict__ WbTh,
                                              const ushortT* __restrict__ WbTl,
                                              const int* __restrict__ adj,
                                              unsigned* __restrict__ adjbit,
                                              ushortT* __restrict__ WhT,
                                              float* __restrict__ src1,
                                              float* __restrict__ dst1) {
    __shared__ ushortT Ah[128 * 64], Al[128 * 64];    // 32 KB
    __shared__ ushortT Bh[128 * 64], Bl[128 * 64];    // 32 KB
    __shared__ float sred[8][32], dred[8][32];
    const int tid = threadIdx.x;
    if (blockIdx.x >= 256) {
        const int g = (blockIdx.x - 256) * 512 + tid;     // 262144 words
        const int row = g >> 5, w = g & 31;
        const int4* p = (const int4*)(adj + (size_t)row * NN + w * 32);
        unsigned m = 0;
#pragma unroll
        for (int q = 0; q < 8; ++q) {
            const int4 v = p[q];
            m |= (v.x > 0 ? 1u : 0u) << (q * 4 + 0);
            m |= (v.y > 0 ? 1u : 0u) << (q * 4 + 1);
            m |= (v.z > 0 ? 1u : 0u) << (q * 4 + 2);
            m |= (v.w > 0 ? 1u : 0u) << (q * 4 + 3);
        }
        adjbit[g] = m;
        return;
    }
    const int lane = tid & 63, wave = tid >> 6;
    const int h = blockIdx.x >> 6, mt = blockIdx.x & 63;
    const int r0 = mt * 128, b = r0 >> 10, jr = r0 & 1023;
    const int m16 = lane & 15, quad = lane >> 4;
    const int mg = wave >> 1, fg = wave & 1;
    const int arow = tid >> 2, apart = tid & 3;
    f32x4 acc[2][4];
#pragma unroll
    for (int a = 0; a < 2; ++a)
#pragma unroll
        for (int c = 0; c < 4; ++c) acc[a][c] = (f32x4){0.f, 0.f, 0.f, 0.f};

    for (int kt = 0; kt < 4; ++kt) {
        __syncthreads();
        const ushortT* planeH = WbTh + (size_t)((h * 4 + kt) * 128) * 64;
        const ushortT* planeL = WbTl + (size_t)((h * 4 + kt) * 128) * 64;
#pragma unroll
        for (int half = 0; half < 2; ++half) {
            const int f = wave * 16 + half * 8 + (lane >> 3);
            const int sc = (lane & 7) ^ (f & 7);
            gload16(planeH + (size_t)f * 64 + sc * 8, Bh + (wave * 16 + half * 8) * 64);
            gload16(planeL + (size_t)f * 64 + sc * 8, Bl + (wave * 16 + half * 8) * 64);
        }
        {
            const float4* xs = (const float4*)(x + (size_t)(r0 + arow) * DIN + kt * 64 + apart * 16);
            union { ushortT u[16]; uint4 q[2]; } th, tl;
#pragma unroll
            for (int e = 0; e < 4; ++e) {
                const float4 v = xs[e];
                split2(v.x, th.u[e * 4 + 0], tl.u[e * 4 + 0]);
                split2(v.y, th.u[e * 4 + 1], tl.u[e * 4 + 1]);
                split2(v.z, th.u[e * 4 + 2], tl.u[e * 4 + 2]);
                split2(v.w, th.u[e * 4 + 3], tl.u[e * 4 + 3]);
            }
            const int s0 = (2 * apart) ^ (arow & 7), s1 = (2 * apart + 1) ^ (arow & 7);
            *(uint4*)&Ah[arow * 64 + s0 * 8] = th.q[0];
            *(uint4*)&Ah[arow * 64 + s1 * 8] = th.q[1];
            *(uint4*)&Al[arow * 64 + s0 * 8] = tl.q[0];
            *(uint4*)&Al[arow * 64 + s1 * 8] = tl.q[1];
        }
        __syncthreads();
#pragma unroll
        for (int ks = 0; ks < 2; ++ks) {
            bf16x8 a_h[2], a_l[2], b_h[4], b_l[4];
#pragma unroll
            for (int ms = 0; ms < 2; ++ms) {
                const int row = (mg * 2 + ms) * 16 + m16;
                const int cl = (ks * 4 + quad) ^ (row & 7);
                a_h[ms] = *(const bf16x8*)&Ah[row * 64 + cl * 8];
                a_l[ms] = *(const bf16x8*)&Al[row * 64 + cl * 8];
            }
#pragma unroll
            for (int fs = 0; fs < 4; ++fs) {
                const int row = (fg * 4 + fs) * 16 + m16;
                const int cl = (ks * 4 + quad) ^ (row & 7);
                b_h[fs] = *(const bf16x8*)&Bh[row * 64 + cl * 8];
                b_l[fs] = *(const bf16x8*)&Bl[row * 64 + cl * 8];
            }
#pragma unroll
            for (int ms = 0; ms < 2; ++ms)
#pragma unroll
                for (int fs = 0; fs < 4; ++fs) {
                    acc[ms][fs] = __builtin_amdgcn_mfma_f32_16x16x32_bf16(a_h[ms], b_h[fs], acc[ms][fs], 0, 0, 0);
                    acc[ms][fs] = __builtin_amdgcn_mfma_f32_16x16x32_bf16(a_h[ms], b_l[fs], acc[ms][fs], 0, 0, 0);
                    acc[ms][fs] = __builtin_amdgcn_mfma_f32_16x16x32_bf16(a_l[ms], b_h[fs], acc[ms][fs], 0, 0, 0);
                }
        }
    }
    float sacc[2][4] = {{0,0,0,0},{0,0,0,0}}, dacc[2][4] = {{0,0,0,0},{0,0,0,0}};
#pragma unroll
    for (int ms = 0; ms < 2; ++ms)
#pragma unroll
        for (int fs = 0; fs < 4; ++fs) {
            const int fl = (fg * 4 + fs) * 16 + m16;
            const float a_s = ah_[h * 2 * DH + fl];
            const float a_d = ah_[h * 2 * DH + DH + fl];
            union { ushortT u[4]; uint2 q; } tw;
#pragma unroll
            for (int reg = 0; reg < 4; ++reg) {
                const float v = acc[ms][fs][reg];
                sacc[ms][reg] += v * a_s;
                dacc[ms][reg] += v * a_d;
                tw.u[reg] = f2bf(v);
            }
            *(uint2*)(WhT + ((size_t)((b * NH + h) * DH + fl)) * NN + jr + (mg * 2 + ms) * 16 + quad * 4) = tw.q;
        }
#pragma unroll
    for (int ms = 0; ms < 2; ++ms) {
#pragma unroll
        for (int reg = 0; reg < 4; ++reg) {
            float s = sacc[ms][reg], d = dacc[ms][reg];
#pragma unroll
            for (int o = 8; o > 0; o >>= 1) {
                s += __shfl_xor(s, o, 64);
                d += __shfl_xor(d, o, 64);
            }
            if (m16 == 0) {
                sred[wave][ms * 16 + quad * 4 + reg] = s;
                dred[wave][ms * 16 + quad * 4 + reg] = d;
            }
        }
    }
    __syncthreads();
    if (tid < 128) {
        const int mgr = tid >> 5, idx = tid & 31;
        src1[h * RTOT + r0 + tid] = sred[mgr * 2][idx] + sred[mgr * 2 + 1][idx];
        dst1[h * RTOT + r0 + tid] = dred[mgr * 2][idx] + dred[mgr * 2 + 1][idx];
    }
}

// ============ k_attn1: fused single-pass softmax + PV GEMM (layer 1) ============
// grid 512 (bh = bx&31 -> b*4+h, it = bx>>5), 512 thr, tile M=64, F=128, K=1024 (16 kt)
// __launch_bounds__(512, 8): force VGPR<=64 so 4 blocks/CU co-reside (LDS 4x37.9KB fits 160KB).
// R9 regression root cause: epilogue change pushed VGPR 52->96, halving resident blocks.
__global__ __launch_bounds__(512, 8) void k_attn1(const unsigned* __restrict__ adjbit,
                                               const ushortT* __restrict__ WhT,
                                               const float* __restrict__ src1,
                                               const float* __restrict__ dst1,
                                               ushortT* __restrict__ xcat) {
    __shared__ ushortT As[64 * 64];                  // 8 KB
    __shared__ ushortT Bs[128 * 64];                 // 16 KB
    __shared__ unsigned maskS[64 * 32];              // 8 KB
    __shared__ float dstv[NN];                       // 4 KB
    __shared__ float srcv[64], rowinv[64], red8[8];
    const int tid = threadIdx.x, lane = tid & 63, wave = tid >> 6;
    const int bh = blockIdx.x & 31, it = blockIdx.x >> 5;
    const int b = bh >> 2, h = bh & 3;
    const int i0 = it * 64;
    const int m16 = lane & 15, quad = lane >> 4;
    const int mg = wave >> 1, fg = wave & 1;

    const unsigned* mbase = adjbit + (size_t)(b * NN + i0) * 32;
#pragma unroll
    for (int k2 = 0; k2 < 4; ++k2) maskS[tid + 512 * k2] = mbase[tid + 512 * k2];
    const float d0 = dst1[h * RTOT + b * NN + tid];
    const float d1 = dst1[h * RTOT + b * NN + tid + 512];
    dstv[tid] = d0; dstv[tid + 512] = d1;
    if (tid < 64) srcv[tid] = src1[h * RTOT + b * NN + i0 + tid];
    float lm = fmaxf(d0, d1);
#pragma unroll
    for (int o = 32; o > 0; o >>= 1) lm = fmaxf(lm, __shfl_xor(lm, o, 64));
    if (lane == 0) red8[wave] = lm;
    __syncthreads();
    const float dmax = fmaxf(fmaxf(fmaxf(red8[0], red8[1]), fmaxf(red8[2], red8[3])),
                             fmaxf(fmaxf(red8[4], red8[5]), fmaxf(red8[6], red8[7])));

    const int arow = tid >> 3, apart = tid & 7;      // 64 rows x 8 parts
    const float si = srcv[arow];
    float mrow = si + dmax;
    mrow = mrow >= 0.f ? mrow : ALPHA * mrow;        // per-row max (monotone leaky)
    float fsum = 0.f;

    const ushortT* Bbase = WhT + (size_t)(bh * DH) * NN;
    f32x4 acc[4];
#pragma unroll
    for (int c = 0; c < 4; ++c) acc[c] = (f32x4){0.f, 0.f, 0.f, 0.f};

    for (int kt = 0; kt < 16; ++kt) {
        __syncthreads();
#pragma unroll
        for (int half = 0; half < 2; ++half) {
            const int f = wave * 16 + half * 8 + (lane >> 3);
            gload16(Bbase + (size_t)f * NN + kt * 64 + (((lane & 7) ^ (f & 7)) * 8),
                    Bs + (wave * 16 + half * 8) * 64);
        }
        {
            const unsigned w0 = maskS[arow * 32 + kt * 2 + (apart >> 2)];
            const int bb = (apart & 3) * 8;
            union { ushortT u[8]; uint4 q; } tw;
#pragma unroll
            for (int e4 = 0; e4 < 2; ++e4) {
                const float4 dv = *(const float4*)&dstv[kt * 64 + apart * 8 + e4 * 4];
                const float vv[4] = {dv.x, dv.y, dv.z, dv.w};
#pragma unroll
                for (int e = 0; e < 4; ++e) {
                    float v = si + vv[e];
                    v = v >= 0.f ? v : ALPHA * v;
                    const unsigned bit = (w0 >> (bb + e4 * 4 + e)) & 1u;
                    const float p = bit ? __expf(v - mrow) : 0.f;
                    fsum += p;
                    tw.u[e4 * 4 + e] = f2bf(p);
                }
            }
            *(uint4*)&As[arow * 64 + (apart ^ (arow & 7)) * 8] = tw.q;
        }
        __syncthreads();
#pragma unroll
        for (int ks = 0; ks < 2; ++ks) {
            const int rowa = mg * 16 + m16;
            const int cla = (ks * 4 + quad) ^ (rowa & 7);
            const bf16x8 afr = *(const bf16x8*)&As[rowa * 64 + cla * 8];
#pragma unroll
            for (int fs = 0; fs < 4; ++fs) {
                const int rowb = fg * 64 + fs * 16 + m16;
                const int clb = (ks * 4 + quad) ^ (rowb & 7);
                const bf16x8 bfr = *(const bf16x8*)&Bs[rowb * 64 + clb * 8];
                acc[fs] = __builtin_amdgcn_mfma_f32_16x16x32_bf16(afr, bfr, acc[fs], 0, 0, 0);
            }
        }
    }
#pragma unroll
    for (int o = 1; o < 8; o <<= 1) fsum += __shfl_xor(fsum, o, 64);
    if ((lane & 7) == 0) rowinv[arow] = 1.f / fsum;
    __syncthreads();
    float rv[4];
#pragma unroll
    for (int reg = 0; reg < 4; ++reg) rv[reg] = rowinv[mg * 16 + quad * 4 + reg];
#pragma unroll
    for (int fs = 0; fs < 4; ++fs) {
        const int f = h * DH + fg * 64 + fs * 16 + m16;
#pragma unroll
        for (int reg = 0; reg < 4; ++reg) {
            const int i = i0 + mg * 16 + quad * 4 + reg;
            xcat[(size_t)(b * NN + i) * FCAT + f] = f2bf(acc[fs][reg] * rv[reg]);
        }
    }
}

// ============ k_wh2: Wh2 = xcat @ W_out, staged GEMM, fused Wh2T + src2/dst2 ============
// grid 256 (r0 = bx*32), 256 thr (4 waves), tile M=32, F=64, K=512 (8 kt)
__global__ __launch_bounds__(256) void k_wh2(const ushortT* __restrict__ xcat,
                                             const ushortT* __restrict__ WoTh,
                                             const ushortT* __restrict__ WoTl,
                                             const float* __restrict__ aout,
                                             ushortT* __restrict__ Wh2T,
                                             float* __restrict__ src2,
                                             float* __restrict__ dst2) {
    __shared__ ushortT As[32 * 64];                  // 4 KB
    __shared__ ushortT Bh[64 * 64], Bl[64 * 64];     // 16 KB
    __shared__ float sred[4][16], dred[4][16];
    const int tid = threadIdx.x, lane = tid & 63, wave = tid >> 6;
    const int r0 = blockIdx.x * 32;
    const int b = r0 >> 10, jr = r0 & 1023;
    const int m16 = lane & 15, quad = lane >> 4;
    const int mg = wave >> 1, fg = wave & 1;         // mg: row-frag 0..1, fg: f-half 0..1
    f32x4 acc[2] = {(f32x4){0.f,0.f,0.f,0.f}, (f32x4){0.f,0.f,0.f,0.f}};

    for (int kt = 0; kt < 8; ++kt) {
        __syncthreads();
        {   // A: 32 rows of xcat, wave covers 8 rows
            const int row = wave * 8 + (lane >> 3);
            const int sc = (lane & 7) ^ (row & 7);
            gload16(xcat + (size_t)(r0 + row) * FCAT + kt * 64 + sc * 8, As + wave * 8 * 64);
        }
#pragma unroll
        for (int half = 0; half < 2; ++half) {   // B: 64 f-rows, wave covers 16
            const int f = wave * 16 + half * 8 + (lane >> 3);
            const int sc = (lane & 7) ^ (f & 7);
            gload16(WoTh + (size_t)f * FCAT + kt * 64 + sc * 8, Bh + (wave * 16 + half * 8) * 64);
            gload16(WoTl + (size_t)f * FCAT + kt * 64 + sc * 8, Bl + (wave * 16 + half * 8) * 64);
        }
        __syncthreads();
#pragma unroll
        for (int ks = 0; ks < 2; ++ks) {
            const int rowa = mg * 16 + m16;
            const int cla = (ks * 4 + quad) ^ (rowa & 7);
            const bf16x8 afr = *(const bf16x8*)&As[rowa * 64 + cla * 8];
#pragma unroll
            for (int ff = 0; ff < 2; ++ff) {
                const int rowb = fg * 32 + ff * 16 + m16;
                const int clb = (ks * 4 + quad) ^ (rowb & 7);
                const bf16x8 b_h = *(const bf16x8*)&Bh[rowb * 64 + clb * 8];
                const bf16x8 b_l = *(const bf16x8*)&Bl[rowb * 64 + clb * 8];
                acc[ff] = __builtin_amdgcn_mfma_f32_16x16x32_bf16(afr, b_h, acc[ff], 0, 0, 0);
                acc[ff] = __builtin_amdgcn_mfma_f32_16x16x32_bf16(afr, b_l, acc[ff], 0, 0, 0);
            }
        }
    }
    // epilogue: Wh2T bf16 + fused src2/dst2 partials
    float sv[4] = {0, 0, 0, 0}, dv[4] = {0, 0, 0, 0};
#pragma unroll
    for (int ff = 0; ff < 2; ++ff) {
        const int f = fg * 32 + ff * 16 + m16;
        const float a_s = aout[f], a_d = aout[DOUT + f];
        union { ushortT u[4]; uint2 q; } tw;
#pragma unroll
        for (int reg = 0; reg < 4; ++reg) {
            const float v = acc[ff][reg];
            sv[reg] += v * a_s;
            dv[reg] += v * a_d;
            tw.u[reg] = f2bf(v);
        }
        *(uint2*)(Wh2T + ((size_t)(b * DOUT + f)) * NN + jr + mg * 16 + quad * 4) = tw.q;
    }
#pragma unroll
    for (int reg = 0; reg < 4; ++reg) {
#pragma unroll
        for (int o = 8; o > 0; o >>= 1) {
            sv[reg] += __shfl_xor(sv[reg], o, 64);
            dv[reg] += __shfl_xor(dv[reg], o, 64);
        }
        if (m16 == 0) { sred[wave][quad * 4 + reg] = sv[reg]; dred[wave][quad * 4 + reg] = dv[reg]; }
    }
    __syncthreads();
    if (tid < 32) {
        const int mgr = tid >> 4, idx = tid & 15;
        src2[r0 + tid] = sred[mgr * 2][idx] + sred[mgr * 2 + 1][idx];
        dst2[r0 + tid] = dred[mgr * 2][idx] + dred[mgr * 2 + 1][idx];
    }
}

// ============ k_attn2: single-pass softmax + PV + ELU + FC + ReLU (layer 2) ============
// grid 256 (b = bx&7, it = bx>>3), 256 thr, tile M=32, F=64, K=1024 (16 kt)
__global__ __launch_bounds__(256) void k_attn2(const unsigned* __restrict__ adjbit,
                                               const ushortT* __restrict__ Wh2T,
                                               const float* __restrict__ src2,
                                               const float* __restrict__ dst2,
                                               const float* __restrict__ Wf,
                                               const float* __restrict__ bfv,
                                               float* __restrict__ out) {
    __shared__ ushortT As[32 * 64];                 // 4 KB
    __shared__ ushortT Bs[64 * 64];                 // 8 KB
    __shared__ unsigned maskS[32 * 32];             // 4 KB
    __shared__ float dstv[NN];                      // 4 KB
    __shared__ ushortT Wfh[64 * 64], Wfl[64 * 64];  // 16 KB
    __shared__ float t2s[32 * 68];                  // 8.5 KB
    __shared__ float srcv[32], rowinv[32], red4[4];
    const int tid = threadIdx.x, lane = tid & 63, wave = tid >> 6;
    const int b = blockIdx.x & 7, it = blockIdx.x >> 3;
    const int i0 = it * 32;
    const int m16 = lane & 15, quad = lane >> 4;

    const unsigned* mbase = adjbit + (size_t)(b * NN + i0) * 32;
#pragma unroll
    for (int k2 = 0; k2 < 4; ++k2) maskS[tid + 256 * k2] = mbase[tid + 256 * k2];
    float lm = -INFINITY;
#pragma unroll
    for (int k2 = 0; k2 < 4; ++k2) {
        const float d = dst2[b * NN + tid + 256 * k2];
        dstv[tid + 256 * k2] = d;
        lm = fmaxf(lm, d);
    }
    if (tid < 32) srcv[tid] = src2[b * NN + i0 + tid];
    {   // stage Wf as hi/lo, layout [c][k] swizzled
        const int c = tid & 63, kc = (tid >> 6) * 16;
        union { ushortT u[16]; uint4 q[2]; } th, tl;
#pragma unroll
        for (int e = 0; e < 16; ++e)
            split2(Wf[(size_t)(kc + e) * DOUT + c], th.u[e], tl.u[e]);
        const int s0 = ((tid >> 6) * 2) ^ (c & 7), s1 = ((tid >> 6) * 2 + 1) ^ (c & 7);
        *(uint4*)&Wfh[c * 64 + s0 * 8] = th.q[0];
        *(uint4*)&Wfh[c * 64 + s1 * 8] = th.q[1];
        *(uint4*)&Wfl[c * 64 + s0 * 8] = tl.q[0];
        *(uint4*)&Wfl[c * 64 + s1 * 8] = tl.q[1];
    }
#pragma unroll
    for (int o = 32; o > 0; o >>= 1) lm = fmaxf(lm, __shfl_xor(lm, o, 64));
    if (lane == 0) red4[wave] = lm;
    __syncthreads();
    const float dmax = fmaxf(fmaxf(red4[0], red4[1]), fmaxf(red4[2], red4[3]));

    const int arow = tid >> 3, apart = tid & 7;      // 32 rows x 8 parts
    const float si = srcv[arow];
    float mrow = si + dmax;
    mrow = mrow >= 0.f ? mrow : ALPHA * mrow;
    float fsum = 0.f;

    const int mfrag = wave >> 1, fh = wave & 1;
    const ushortT* Bbase = Wh2T + (size_t)(b * DOUT) * NN;
    f32x4 acc[2] = {(f32x4){0.f,0.f,0.f,0.f}, (f32x4){0.f,0.f,0.f,0.f}};

    for (int kt = 0; kt < 16; ++kt) {
        __syncthreads();
#pragma unroll
        for (int half = 0; half < 2; ++half) {
            const int f = wave * 16 + half * 8 + (lane >> 3);
            gload16(Bbase + (size_t)f * NN + kt * 64 + (((lane & 7) ^ (f & 7)) * 8),
                    Bs + (wave * 16 + half * 8) * 64);
        }
        {
            const unsigned w0 = maskS[arow * 32 + kt * 2 + (apart >> 2)];
            const int bb = (apart & 3) * 8;
            union { ushortT u[8]; uint4 q; } tw;
#pragma unroll
            for (int e4 = 0; e4 < 2; ++e4) {
                const float4 dv = *(const float4*)&dstv[kt * 64 + apart * 8 + e4 * 4];
                const float vv[4] = {dv.x, dv.y, dv.z, dv.w};
#pragma unroll
                for (int e = 0; e < 4; ++e) {
                    float v = si + vv[e];
                    v = v >= 0.f ? v : ALPHA * v;
                    const unsigned bit = (w0 >> (bb + e4 * 4 + e)) & 1u;
                    const float p = bit ? __expf(v - mrow) : 0.f;
                    fsum += p;
                    tw.u[e4 * 4 + e] = f2bf(p);
                }
            }
            *(uint4*)&As[arow * 64 + (apart ^ (arow & 7)) * 8] = tw.q;
        }
        __syncthreads();
#pragma unroll
        for (int ks = 0; ks < 2; ++ks) {
            const int rowa = mfrag * 16 + m16;
            const int cla = (ks * 4 + quad) ^ (rowa & 7);
            const bf16x8 afr = *(const bf16x8*)&As[rowa * 64 + cla * 8];
#pragma unroll
            for (int ff = 0; ff < 2; ++ff) {
                const int rowb = (fh * 2 + ff) * 16 + m16;
                const int clb = (ks * 4 + quad) ^ (rowb & 7);
                const bf16x8 bfr = *(const bf16x8*)&Bs[rowb * 64 + clb * 8];
                acc[ff] = __builtin_amdgcn_mfma_f32_16x16x32_bf16(afr, bfr, acc[ff], 0, 0, 0);
            }
        }
    }
#pragma unroll
    for (int o = 1; o < 8; o <<= 1) fsum += __shfl_xor(fsum, o, 64);
    if ((lane & 7) == 0) rowinv[arow] = 1.f / fsum;
    __syncthreads();
#pragma unroll
    for (int ff = 0; ff < 2; ++ff) {
#pragma unroll
        for (int reg = 0; reg < 4; ++reg) {
            const int row = mfrag * 16 + quad * 4 + reg;
            float v = acc[ff][reg] * rowinv[row];
            v = v > 0.f ? v : (__expf(v) - 1.f);
            t2s[row * 68 + (fh * 2 + ff) * 16 + m16] = v;
        }
    }
    __syncthreads();
    const int mf = wave >> 1, nh = wave & 1;
    f32x4 oacc[2];
#pragma unroll
    for (int g = 0; g < 2; ++g) {
        const float bias = bfv[(nh * 2 + g) * 16 + m16];
        oacc[g] = (f32x4){bias, bias, bias, bias};
    }
#pragma unroll
    for (int ks = 0; ks < 2; ++ks) {
        const int rowa = mf * 16 + m16;
        const float4 fA = *(const float4*)&t2s[rowa * 68 + ks * 32 + quad * 8];
        const float4 fB = *(const float4*)&t2s[rowa * 68 + ks * 32 + quad * 8 + 4];
        union { ushortT u[8]; bf16x8 v; } a_h, a_l;
        const float av[8] = {fA.x, fA.y, fA.z, fA.w, fB.x, fB.y, fB.z, fB.w};
#pragma unroll
        for (int e = 0; e < 8; ++e) split2(av[e], a_h.u[e], a_l.u[e]);
#pragma unroll
        for (int g = 0; g < 2; ++g) {
            const int rowc = (nh * 2 + g) * 16 + m16;
            const int cl = (ks * 4 + quad) ^ (rowc & 7);
            const bf16x8 b_h = *(const bf16x8*)&Wfh[rowc * 64 + cl * 8];
            const bf16x8 b_l = *(const bf16x8*)&Wfl[rowc * 64 + cl * 8];
            oacc[g] = __builtin_amdgcn_mfma_f32_16x16x32_bf16(a_h.v, b_h, oacc[g], 0, 0, 0);
            oacc[g] = __builtin_amdgcn_mfma_f32_16x16x32_bf16(a_h.v, b_l, oacc[g], 0, 0, 0);
            oacc[g] = __builtin_amdgcn_mfma_f32_16x16x32_bf16(a_l.v, b_h, oacc[g], 0, 0, 0);
        }
    }
#pragma unroll
    for (int g = 0; g < 2; ++g) {
        const int c = (nh * 2 + g) * 16 + m16;
#pragma unroll
        for (int reg = 0; reg < 4; ++reg) {
            const int i = i0 + mf * 16 + quad * 4 + reg;
            out[(size_t)(b * NN + i) * DOUT + c] = fmaxf(oacc[g][reg], 0.f);
        }
    }
}

extern "C" void kernel_launch(void* const* d_in, const int* in_sizes, int n_in,
                              void* d_out, int out_size, void* d_ws, size_t ws_size,
                              hipStream_t stream) {
    const float* x   = (const float*)d_in[0];
    const int*   adj = (const int*)d_in[1];
    const float* Wh  = (const float*)d_in[2];
    const float* ah  = (const float*)d_in[3];
    const float* Wo  = (const float*)d_in[4];
    const float* ao  = (const float*)d_in[5];
    const float* Wf  = (const float*)d_in[6];
    const float* bf  = (const float*)d_in[7];
    float* out = (float*)d_out;

    float* ws    = (float*)d_ws;
    float* src1  = ws;                                 // 4*8192
    float* dst1  = src1 + NH * RTOT;                   // 4*8192
    float* src2  = dst1 + NH * RTOT;                   // 8192
    float* dst2  = src2 + RTOT;                        // 8192
    ushortT* WhT   = (ushortT*)(dst2 + RTOT);                // 8192*512 bf16
    ushortT* Wh2T  = WhT + (size_t)RTOT * FCAT;              // 8192*64
    ushortT* xcat  = Wh2T + (size_t)RTOT * DOUT;             // 8192*512
    ushortT* WbTh  = xcat + (size_t)RTOT * FCAT;             // 131072
    ushortT* WbTl  = WbTh + NH * DH * DIN;
    ushortT* WoTh  = WbTl + NH * DH * DIN;                   // 32768
    ushortT* WoTl  = WoTh + DOUT * FCAT;
    unsigned* adjbit = (unsigned*)(WoTl + DOUT * FCAT);      // 262144 words

    hipLaunchKernelGGL(k_prepw, dim3((NH * DH * DIN + DOUT * FCAT) / 256), dim3(256), 0, stream,
                       Wh, Wo, WbTh, WbTl, WoTh, WoTl);
    hipLaunchKernelGGL(k_main,  dim3(768), dim3(512), 0, stream,
                       x, ah, WbTh, WbTl, adj, adjbit, WhT, src1, dst1);
    hipLaunchKernelGGL(k_attn1, dim3(512), dim3(512), 0, stream,
                       adjbit, WhT, src1, dst1, xcat);
    hipLaunchKernelGGL(k_wh2,   dim3(256), dim3(256), 0, stream,
                       xcat, WoTh, WoTl, ao, Wh2T, src2, dst2);
    hipLaunchKernelGGL(k_attn2, dim3(256), dim3(256), 0, stream,
                       adjbit, Wh2T, src2, dst2, Wf, bf, out);
}

// Round 11
// 158.644 us; speedup vs baseline: 1.3032x; 1.3032x over previous
//
#include <hip/hip_runtime.h>
#include <hip/hip_bf16.h>

// Shapes (fixed by reference): B=8, N=1024, Din=256, H=4, Dh=128, Do=64
#define BSZ 8
#define NN 1024
#define DIN 256
#define NH 4
#define DH 128
#define DOUT 64
#define RTOT (BSZ*NN)          // 8192 rows total
#define FCAT (NH*DH)           // 512
#define ALPHA 0.2f

typedef unsigned short ushortT;
typedef __attribute__((ext_vector_type(8))) short bf16x8;
typedef __attribute__((ext_vector_type(4))) float f32x4;

static __device__ __forceinline__ ushortT f2bf(float f) {
    __hip_bfloat16 h = __float2bfloat16(f);
    return *reinterpret_cast<ushortT*>(&h);
}
static __device__ __forceinline__ float bfu2f(ushortT u) {
    return __uint_as_float(((unsigned)u) << 16);
}
static __device__ __forceinline__ void split2(float v, ushortT& hi, ushortT& lo) {
    hi = f2bf(v);
    lo = f2bf(v - bfu2f(hi));
}
// async global->LDS, 16B per lane; LDS dest = base(wave-uniform) + lane*16
static __device__ __forceinline__ void gload16(const ushortT* g, ushortT* l) {
    __builtin_amdgcn_global_load_lds(
        (const __attribute__((address_space(1))) unsigned int*)(const void*)g,
        (__attribute__((address_space(3))) unsigned int*)(void*)l, 16, 0, 0);
}

// ============ k_prepw: weight transforms only (bf16 hi/lo, k-contig) ============
__global__ __launch_bounds__(256) void k_prepw(const float* __restrict__ W,
                                               const float* __restrict__ Wout,
                                               ushortT* __restrict__ WbTh, ushortT* __restrict__ WbTl,
                                               ushortT* __restrict__ WoTh, ushortT* __restrict__ WoTl) {
    const int g2 = blockIdx.x * 256 + threadIdx.x;
    if (g2 < NH * DH * DIN) {           // 131072
        const int h = g2 >> 15, f = (g2 >> 8) & 127, k = g2 & 255;
        const int kt = k >> 6, k64 = k & 63;
        const float v = W[(size_t)h * DIN * DH + (size_t)k * DH + f];
        ushortT hi, lo; split2(v, hi, lo);
        const int idx = ((h * 4 + kt) * 128 + f) * 64 + k64;
        WbTh[idx] = hi; WbTl[idx] = lo;
    } else {
        const int g3 = g2 - NH * DH * DIN;   // < 32768
        const int f = g3 >> 9, k = g3 & 511;
        const float v = Wout[(size_t)k * DOUT + f];
        ushortT hi, lo; split2(v, hi, lo);
        WoTh[g3] = hi; WoTl[g3] = lo;
    }
}

// ============ k_main: blocks 0..255 = wh1 MFMA GEMM; blocks 256..767 = adj bit-pack ============
__global__ __launch_bounds__(512) void k_main(const float* __restrict__ x,
                                              const float* __restrict__ ah_,
                                              const ushortT* __restrict__ WbTh,
                                              const ushortT* __restrict__ WbTl,
                                              const int* __restrict__ adj,
                                              unsigned* __restrict__ adjbit,
                                              ushortT* __restrict__ WhT,
                                              float* __restrict__ src1,
                                              float* __restrict__ dst1) {
    __shared__ ushortT Ah[128 * 64], Al[128 * 64];    // 32 KB
    __shared__ ushortT Bh[128 * 64], Bl[128 * 64];    // 32 KB
    __shared__ float sred[8][32], dred[8][32];
    const int tid = threadIdx.x;
    if (blockIdx.x >= 256) {
        const int g = (blockIdx.x - 256) * 512 + tid;     // 262144 words
        const int row = g >> 5, w = g & 31;
        const int4* p = (const int4*)(adj + (size_t)row * NN + w * 32);
        unsigned m = 0;
#pragma unroll
        for (int q = 0; q < 8; ++q) {
            const int4 v = p[q];
            m |= (v.x > 0 ? 1u : 0u) << (q * 4 + 0);
            m |= (v.y > 0 ? 1u : 0u) << (q * 4 + 1);
            m |= (v.z > 0 ? 1u : 0u) << (q * 4 + 2);
            m |= (v.w > 0 ? 1u : 0u) << (q * 4 + 3);
        }
        adjbit[g] = m;
        return;
    }
    const int lane = tid & 63, wave = tid >> 6;
    const int h = blockIdx.x >> 6, mt = blockIdx.x & 63;
    const int r0 = mt * 128, b = r0 >> 10, jr = r0 & 1023;
    const int m16 = lane & 15, quad = lane >> 4;
    const int mg = wave >> 1, fg = wave & 1;
    const int arow = tid >> 2, apart = tid & 3;
    f32x4 acc[2][4];
#pragma unroll
    for (int a = 0; a < 2; ++a)
#pragma unroll
        for (int c = 0; c < 4; ++c) acc[a][c] = (f32x4){0.f, 0.f, 0.f, 0.f};

    for (int kt = 0; kt < 4; ++kt) {
        __syncthreads();
        const ushortT* planeH = WbTh + (size_t)((h * 4 + kt) * 128) * 64;
        const ushortT* planeL = WbTl + (size_t)((h * 4 + kt) * 128) * 64;
#pragma unroll
        for (int half = 0; half < 2; ++half) {
            const int f = wave * 16 + half * 8 + (lane >> 3);
            const int sc = (lane & 7) ^ (f & 7);
            gload16(planeH + (size_t)f * 64 + sc * 8, Bh + (wave * 16 + half * 8) * 64);
            gload16(planeL + (size_t)f * 64 + sc * 8, Bl + (wave * 16 + half * 8) * 64);
        }
        {
            const float4* xs = (const float4*)(x + (size_t)(r0 + arow) * DIN + kt * 64 + apart * 16);
            union { ushortT u[16]; uint4 q[2]; } th, tl;
#pragma unroll
            for (int e = 0; e < 4; ++e) {
                const float4 v = xs[e];
                split2(v.x, th.u[e * 4 + 0], tl.u[e * 4 + 0]);
                split2(v.y, th.u[e * 4 + 1], tl.u[e * 4 + 1]);
                split2(v.z, th.u[e * 4 + 2], tl.u[e * 4 + 2]);
                split2(v.w, th.u[e * 4 + 3], tl.u[e * 4 + 3]);
            }
            const int s0 = (2 * apart) ^ (arow & 7), s1 = (2 * apart + 1) ^ (arow & 7);
            *(uint4*)&Ah[arow * 64 + s0 * 8] = th.q[0];
            *(uint4*)&Ah[arow * 64 + s1 * 8] = th.q[1];
            *(uint4*)&Al[arow * 64 + s0 * 8] = tl.q[0];
            *(uint4*)&Al[arow * 64 + s1 * 8] = tl.q[1];
        }
        __syncthreads();
#pragma unroll
        for (int ks = 0; ks < 2; ++ks) {
            bf16x8 a_h[2], a_l[2], b_h[4], b_l[4];
#pragma unroll
            for (int ms = 0; ms < 2; ++ms) {
                const int row = (mg * 2 + ms) * 16 + m16;
                const int cl = (ks * 4 + quad) ^ (row & 7);
                a_h[ms] = *(const bf16x8*)&Ah[row * 64 + cl * 8];
                a_l[ms] = *(const bf16x8*)&Al[row * 64 + cl * 8];
            }
#pragma unroll
            for (int fs = 0; fs < 4; ++fs) {
                const int row = (fg * 4 + fs) * 16 + m16;
                const int cl = (ks * 4 + quad) ^ (row & 7);
                b_h[fs] = *(const bf16x8*)&Bh[row * 64 + cl * 8];
                b_l[fs] = *(const bf16x8*)&Bl[row * 64 + cl * 8];
            }
#pragma unroll
            for (int ms = 0; ms < 2; ++ms)
#pragma unroll
                for (int fs = 0; fs < 4; ++fs) {
                    acc[ms][fs] = __builtin_amdgcn_mfma_f32_16x16x32_bf16(a_h[ms], b_h[fs], acc[ms][fs], 0, 0, 0);
                    acc[ms][fs] = __builtin_amdgcn_mfma_f32_16x16x32_bf16(a_h[ms], b_l[fs], acc[ms][fs], 0, 0, 0);
                    acc[ms][fs] = __builtin_amdgcn_mfma_f32_16x16x32_bf16(a_l[ms], b_h[fs], acc[ms][fs], 0, 0, 0);
                }
        }
    }
    float sacc[2][4] = {{0,0,0,0},{0,0,0,0}}, dacc[2][4] = {{0,0,0,0},{0,0,0,0}};
#pragma unroll
    for (int ms = 0; ms < 2; ++ms)
#pragma unroll
        for (int fs = 0; fs < 4; ++fs) {
            const int fl = (fg * 4 + fs) * 16 + m16;
            const float a_s = ah_[h * 2 * DH + fl];
            const float a_d = ah_[h * 2 * DH + DH + fl];
            union { ushortT u[4]; uint2 q; } tw;
#pragma unroll
            for (int reg = 0; reg < 4; ++reg) {
                const float v = acc[ms][fs][reg];
                sacc[ms][reg] += v * a_s;
                dacc[ms][reg] += v * a_d;
                tw.u[reg] = f2bf(v);
            }
            *(uint2*)(WhT + ((size_t)((b * NH + h) * DH + fl)) * NN + jr + (mg * 2 + ms) * 16 + quad * 4) = tw.q;
        }
#pragma unroll
    for (int ms = 0; ms < 2; ++ms) {
#pragma unroll
        for (int reg = 0; reg < 4; ++reg) {
            float s = sacc[ms][reg], d = dacc[ms][reg];
#pragma unroll
            for (int o = 8; o > 0; o >>= 1) {
                s += __shfl_xor(s, o, 64);
                d += __shfl_xor(d, o, 64);
            }
            if (m16 == 0) {
                sred[wave][ms * 16 + quad * 4 + reg] = s;
                dred[wave][ms * 16 + quad * 4 + reg] = d;
            }
        }
    }
    __syncthreads();
    if (tid < 128) {
        const int mgr = tid >> 5, idx = tid & 31;
        src1[h * RTOT + r0 + tid] = sred[mgr * 2][idx] + sred[mgr * 2 + 1][idx];
        dst1[h * RTOT + r0 + tid] = dred[mgr * 2][idx] + dred[mgr * 2 + 1][idx];
    }
}

// ============ k_attn1: fused single-pass softmax + PV GEMM (layer 1) ============
// grid 1024 (bh = bx&31 -> b*4+h, it = bx>>5), 256 thr (4 waves), tile M=32, F=128, K=1024.
// 256-thr blocks make occupancy robust to VGPR (4 blocks/CU even at ~96 VGPR; LDS 28.4KB).
// Blocks sharing a WhT slice are bx+32k == same XCD (mod 8) -> slice stays in one L2.
// NOTE: do NOT force __launch_bounds__ min-waves here — R10's (512,8) made the allocator
// spill the K-loop (WRITE_SIZE 8->130MB scratch). Shrink blocks instead.
__global__ __launch_bounds__(256) void k_attn1(const unsigned* __restrict__ adjbit,
                                               const ushortT* __restrict__ WhT,
                                               const float* __restrict__ src1,
                                               const float* __restrict__ dst1,
                                               ushortT* __restrict__ xcat) {
    __shared__ ushortT As[32 * 64];                  // 4 KB
    __shared__ ushortT Bs[128 * 64];                 // 16 KB
    __shared__ unsigned maskS[32 * 32];              // 4 KB
    __shared__ float dstv[NN];                       // 4 KB
    __shared__ float srcv[32], rowinv[32], red4[4];
    const int tid = threadIdx.x, lane = tid & 63, wave = tid >> 6;
    const int bh = blockIdx.x & 31, it = blockIdx.x >> 5;
    const int b = bh >> 2, h = bh & 3;
    const int i0 = it * 32;
    const int m16 = lane & 15, quad = lane >> 4;

    const unsigned* mbase = adjbit + (size_t)(b * NN + i0) * 32;
#pragma unroll
    for (int k2 = 0; k2 < 4; ++k2) maskS[tid + 256 * k2] = mbase[tid + 256 * k2];
    float lm = -INFINITY;
#pragma unroll
    for (int k2 = 0; k2 < 4; ++k2) {
        const float d = dst1[h * RTOT + b * NN + tid + 256 * k2];
        dstv[tid + 256 * k2] = d;
        lm = fmaxf(lm, d);
    }
    if (tid < 32) srcv[tid] = src1[h * RTOT + b * NN + i0 + tid];
#pragma unroll
    for (int o = 32; o > 0; o >>= 1) lm = fmaxf(lm, __shfl_xor(lm, o, 64));
    if (lane == 0) red4[wave] = lm;
    __syncthreads();
    const float dmax = fmaxf(fmaxf(red4[0], red4[1]), fmaxf(red4[2], red4[3]));

    const int arow = tid >> 3, apart = tid & 7;      // 32 rows x 8 parts
    const float si = srcv[arow];
    float mrow = si + dmax;
    mrow = mrow >= 0.f ? mrow : ALPHA * mrow;        // per-row max (monotone leaky)
    float fsum = 0.f;

    const ushortT* Bbase = WhT + (size_t)(bh * DH) * NN;
    f32x4 acc[2][2];
#pragma unroll
    for (int a = 0; a < 2; ++a)
#pragma unroll
        for (int c = 0; c < 2; ++c) acc[a][c] = (f32x4){0.f, 0.f, 0.f, 0.f};

    for (int kt = 0; kt < 16; ++kt) {
        __syncthreads();
#pragma unroll
        for (int half = 0; half < 4; ++half) {       // B: 128 f-rows, wave covers 32
            const int f = wave * 32 + half * 8 + (lane >> 3);
            gload16(Bbase + (size_t)f * NN + kt * 64 + (((lane & 7) ^ (f & 7)) * 8),
                    Bs + (wave * 32 + half * 8) * 64);
        }
        {
            const unsigned w0 = maskS[arow * 32 + kt * 2 + (apart >> 2)];
            const int bb = (apart & 3) * 8;
            union { ushortT u[8]; uint4 q; } tw;
#pragma unroll
            for (int e4 = 0; e4 < 2; ++e4) {
                const float4 dv = *(const float4*)&dstv[kt * 64 + apart * 8 + e4 * 4];
                const float vv[4] = {dv.x, dv.y, dv.z, dv.w};
#pragma unroll
                for (int e = 0; e < 4; ++e) {
                    float v = si + vv[e];
                    v = v >= 0.f ? v : ALPHA * v;
                    const unsigned bit = (w0 >> (bb + e4 * 4 + e)) & 1u;
                    const float p = bit ? __expf(v - mrow) : 0.f;
                    fsum += p;
                    tw.u[e4 * 4 + e] = f2bf(p);
                }
            }
            *(uint4*)&As[arow * 64 + (apart ^ (arow & 7)) * 8] = tw.q;
        }
        __syncthreads();
#pragma unroll
        for (int ks = 0; ks < 2; ++ks) {
            bf16x8 afr[2];
#pragma unroll
            for (int ms = 0; ms < 2; ++ms) {
                const int rowa = ms * 16 + m16;
                const int cla = (ks * 4 + quad) ^ (rowa & 7);
                afr[ms] = *(const bf16x8*)&As[rowa * 64 + cla * 8];
            }
#pragma unroll
            for (int ff = 0; ff < 2; ++ff) {
                const int rowb = wave * 32 + ff * 16 + m16;
                const int clb = (ks * 4 + quad) ^ (rowb & 7);
                const bf16x8 bfr = *(const bf16x8*)&Bs[rowb * 64 + clb * 8];
#pragma unroll
                for (int ms = 0; ms < 2; ++ms)
                    acc[ms][ff] = __builtin_amdgcn_mfma_f32_16x16x32_bf16(afr[ms], bfr, acc[ms][ff], 0, 0, 0);
            }
        }
    }
#pragma unroll
    for (int o = 1; o < 8; o <<= 1) fsum += __shfl_xor(fsum, o, 64);
    if ((lane & 7) == 0) rowinv[arow] = 1.f / fsum;
    __syncthreads();
#pragma unroll
    for (int ms = 0; ms < 2; ++ms) {
        float rv[4];
#pragma unroll
        for (int reg = 0; reg < 4; ++reg) rv[reg] = rowinv[ms * 16 + quad * 4 + reg];
#pragma unroll
        for (int ff = 0; ff < 2; ++ff) {
            const int f = h * DH + wave * 32 + ff * 16 + m16;
#pragma unroll
            for (int reg = 0; reg < 4; ++reg) {
                const int i = i0 + ms * 16 + quad * 4 + reg;
                xcat[(size_t)(b * NN + i) * FCAT + f] = f2bf(acc[ms][ff][reg] * rv[reg]);
            }
        }
    }
}

// ============ k_wh2: Wh2 = xcat @ W_out, staged GEMM, fused Wh2T + src2/dst2 ============
// grid 256 (r0 = bx*32), 256 thr (4 waves), tile M=32, F=64, K=512 (8 kt)
__global__ __launch_bounds__(256) void k_wh2(const ushortT* __restrict__ xcat,
                                             const ushortT* __restrict__ WoTh,
                                             const ushortT* __restrict__ WoTl,
                                             const float* __restrict__ aout,
                                             ushortT* __restrict__ Wh2T,
                                             float* __restrict__ src2,
                                             float* __restrict__ dst2) {
    __shared__ ushortT As[32 * 64];                  // 4 KB
    __shared__ ushortT Bh[64 * 64], Bl[64 * 64];     // 16 KB
    __shared__ float sred[4][16], dred[4][16];
    const int tid = threadIdx.x, lane = tid & 63, wave = tid >> 6;
    const int r0 = blockIdx.x * 32;
    const int b = r0 >> 10, jr = r0 & 1023;
    const int m16 = lane & 15, quad = lane >> 4;
    const int mg = wave >> 1, fg = wave & 1;         // mg: row-frag 0..1, fg: f-half 0..1
    f32x4 acc[2] = {(f32x4){0.f,0.f,0.f,0.f}, (f32x4){0.f,0.f,0.f,0.f}};

    for (int kt = 0; kt < 8; ++kt) {
        __syncthreads();
        {   // A: 32 rows of xcat, wave covers 8 rows
            const int row = wave * 8 + (lane >> 3);
            const int sc = (lane & 7) ^ (row & 7);
            gload16(xcat + (size_t)(r0 + row) * FCAT + kt * 64 + sc * 8, As + wave * 8 * 64);
        }
#pragma unroll
        for (int half = 0; half < 2; ++half) {   // B: 64 f-rows, wave covers 16
            const int f = wave * 16 + half * 8 + (lane >> 3);
            const int sc = (lane & 7) ^ (f & 7);
            gload16(WoTh + (size_t)f * FCAT + kt * 64 + sc * 8, Bh + (wave * 16 + half * 8) * 64);
            gload16(WoTl + (size_t)f * FCAT + kt * 64 + sc * 8, Bl + (wave * 16 + half * 8) * 64);
        }
        __syncthreads();
#pragma unroll
        for (int ks = 0; ks < 2; ++ks) {
            const int rowa = mg * 16 + m16;
            const int cla = (ks * 4 + quad) ^ (rowa & 7);
            const bf16x8 afr = *(const bf16x8*)&As[rowa * 64 + cla * 8];
#pragma unroll
            for (int ff = 0; ff < 2; ++ff) {
                const int rowb = fg * 32 + ff * 16 + m16;
                const int clb = (ks * 4 + quad) ^ (rowb & 7);
                const bf16x8 b_h = *(const bf16x8*)&Bh[rowb * 64 + clb * 8];
                const bf16x8 b_l = *(const bf16x8*)&Bl[rowb * 64 + clb * 8];
                acc[ff] = __builtin_amdgcn_mfma_f32_16x16x32_bf16(afr, b_h, acc[ff], 0, 0, 0);
                acc[ff] = __builtin_amdgcn_mfma_f32_16x16x32_bf16(afr, b_l, acc[ff], 0, 0, 0);
            }
        }
    }
    // epilogue: Wh2T bf16 + fused src2/dst2 partials
    float sv[4] = {0, 0, 0, 0}, dv[4] = {0, 0, 0, 0};
#pragma unroll
    for (int ff = 0; ff < 2; ++ff) {
        const int f = fg * 32 + ff * 16 + m16;
        const float a_s = aout[f], a_d = aout[DOUT + f];
        union { ushortT u[4]; uint2 q; } tw;
#pragma unroll
        for (int reg = 0; reg < 4; ++reg) {
            const float v = acc[ff][reg];
            sv[reg] += v * a_s;
            dv[reg] += v * a_d;
            tw.u[reg] = f2bf(v);
        }
        *(uint2*)(Wh2T + ((size_t)(b * DOUT + f)) * NN + jr + mg * 16 + quad * 4) = tw.q;
    }
#pragma unroll
    for (int reg = 0; reg < 4; ++reg) {
#pragma unroll
        for (int o = 8; o > 0; o >>= 1) {
            sv[reg] += __shfl_xor(sv[reg], o, 64);
            dv[reg] += __shfl_xor(dv[reg], o, 64);
        }
        if (m16 == 0) { sred[wave][quad * 4 + reg] = sv[reg]; dred[wave][quad * 4 + reg] = dv[reg]; }
    }
    __syncthreads();
    if (tid < 32) {
        const int mgr = tid >> 4, idx = tid & 15;
        src2[r0 + tid] = sred[mgr * 2][idx] + sred[mgr * 2 + 1][idx];
        dst2[r0 + tid] = dred[mgr * 2][idx] + dred[mgr * 2 + 1][idx];
    }
}

// ============ k_attn2: single-pass softmax + PV + ELU + FC + ReLU (layer 2) ============
// grid 256 (b = bx&7, it = bx>>3), 256 thr, tile M=32, F=64, K=1024 (16 kt)
__global__ __launch_bounds__(256) void k_attn2(const unsigned* __restrict__ adjbit,
                                               const ushortT* __restrict__ Wh2T,
                                               const float* __restrict__ src2,
                                               const float* __restrict__ dst2,
                                               const float* __restrict__ Wf,
                                               const float* __restrict__ bfv,
                                               float* __restrict__ out) {
    __shared__ ushortT As[32 * 64];                 // 4 KB
    __shared__ ushortT Bs[64 * 64];                 // 8 KB
    __shared__ unsigned maskS[32 * 32];             // 4 KB
    __shared__ float dstv[NN];                      // 4 KB
    __shared__ ushortT Wfh[64 * 64], Wfl[64 * 64];  // 16 KB
    __shared__ float t2s[32 * 68];                  // 8.5 KB
    __shared__ float srcv[32], rowinv[32], red4[4];
    const int tid = threadIdx.x, lane = tid & 63, wave = tid >> 6;
    const int b = blockIdx.x & 7, it = blockIdx.x >> 3;
    const int i0 = it * 32;
    const int m16 = lane & 15, quad = lane >> 4;

    const unsigned* mbase = adjbit + (size_t)(b * NN + i0) * 32;
#pragma unroll
    for (int k2 = 0; k2 < 4; ++k2) maskS[tid + 256 * k2] = mbase[tid + 256 * k2];
    float lm = -INFINITY;
#pragma unroll
    for (int k2 = 0; k2 < 4; ++k2) {
        const float d = dst2[b * NN + tid + 256 * k2];
        dstv[tid + 256 * k2] = d;
        lm = fmaxf(lm, d);
    }
    if (tid < 32) srcv[tid] = src2[b * NN + i0 + tid];
    {   // stage Wf as hi/lo, layout [c][k] swizzled
        const int c = tid & 63, kc = (tid >> 6) * 16;
        union { ushortT u[16]; uint4 q[2]; } th, tl;
#pragma unroll
        for (int e = 0; e < 16; ++e)
            split2(Wf[(size_t)(kc + e) * DOUT + c], th.u[e], tl.u[e]);
        const int s0 = ((tid >> 6) * 2) ^ (c & 7), s1 = ((tid >> 6) * 2 + 1) ^ (c & 7);
        *(uint4*)&Wfh[c * 64 + s0 * 8] = th.q[0];
        *(uint4*)&Wfh[c * 64 + s1 * 8] = th.q[1];
        *(uint4*)&Wfl[c * 64 + s0 * 8] = tl.q[0];
        *(uint4*)&Wfl[c * 64 + s1 * 8] = tl.q[1];
    }
#pragma unroll
    for (int o = 32; o > 0; o >>= 1) lm = fmaxf(lm, __shfl_xor(lm, o, 64));
    if (lane == 0) red4[wave] = lm;
    __syncthreads();
    const float dmax = fmaxf(fmaxf(red4[0], red4[1]), fmaxf(red4[2], red4[3]));

    const int arow = tid >> 3, apart = tid & 7;      // 32 rows x 8 parts
    const float si = srcv[arow];
    float mrow = si + dmax;
    mrow = mrow >= 0.f ? mrow : ALPHA * mrow;
    float fsum = 0.f;

    const int mfrag = wave >> 1, fh = wave & 1;
    const ushortT* Bbase = Wh2T + (size_t)(b * DOUT) * NN;
    f32x4 acc[2] = {(f32x4){0.f,0.f,0.f,0.f}, (f32x4){0.f,0.f,0.f,0.f}};

    for (int kt = 0; kt < 16; ++kt) {
        __syncthreads();
#pragma unroll
        for (int half = 0; half < 2; ++half) {
            const int f = wave * 16 + half * 8 + (lane >> 3);
            gload16(Bbase + (size_t)f * NN + kt * 64 + (((lane & 7) ^ (f & 7)) * 8),
                    Bs + (wave * 16 + half * 8) * 64);
        }
        {
            const unsigned w0 = maskS[arow * 32 + kt * 2 + (apart >> 2)];
            const int bb = (apart & 3) * 8;
            union { ushortT u[8]; uint4 q; } tw;
#pragma unroll
            for (int e4 = 0; e4 < 2; ++e4) {
                const float4 dv = *(const float4*)&dstv[kt * 64 + apart * 8 + e4 * 4];
                const float vv[4] = {dv.x, dv.y, dv.z, dv.w};
#pragma unroll
                for (int e = 0; e < 4; ++e) {
                    float v = si + vv[e];
                    v = v >= 0.f ? v : ALPHA * v;
                    const unsigned bit = (w0 >> (bb + e4 * 4 + e)) & 1u;
                    const float p = bit ? __expf(v - mrow) : 0.f;
                    fsum += p;
                    tw.u[e4 * 4 + e] = f2bf(p);
                }
            }
            *(uint4*)&As[arow * 64 + (apart ^ (arow & 7)) * 8] = tw.q;
        }
        __syncthreads();
#pragma unroll
        for (int ks = 0; ks < 2; ++ks) {
            const int rowa = mfrag * 16 + m16;
            const int cla = (ks * 4 + quad) ^ (rowa & 7);
            const bf16x8 afr = *(const bf16x8*)&As[rowa * 64 + cla * 8];
#pragma unroll
            for (int ff = 0; ff < 2; ++ff) {
                const int rowb = (fh * 2 + ff) * 16 + m16;
                const int clb = (ks * 4 + quad) ^ (rowb & 7);
                const bf16x8 bfr = *(const bf16x8*)&Bs[rowb * 64 + clb * 8];
                acc[ff] = __builtin_amdgcn_mfma_f32_16x16x32_bf16(afr, bfr, acc[ff], 0, 0, 0);
            }
        }
    }
#pragma unroll
    for (int o = 1; o < 8; o <<= 1) fsum += __shfl_xor(fsum, o, 64);
    if ((lane & 7) == 0) rowinv[arow] = 1.f / fsum;
    __syncthreads();
#pragma unroll
    for (int ff = 0; ff < 2; ++ff) {
#pragma unroll
        for (int reg = 0; reg < 4; ++reg) {
            const int row = mfrag * 16 + quad * 4 + reg;
            float v = acc[ff][reg] * rowinv[row];
            v = v > 0.f ? v : (__expf(v) - 1.f);
            t2s[row * 68 + (fh * 2 + ff) * 16 + m16] = v;
        }
    }
    __syncthreads();
    const int mf = wave >> 1, nh = wave & 1;
    f32x4 oacc[2];
#pragma unroll
    for (int g = 0; g < 2; ++g) {
        const float bias = bfv[(nh * 2 + g) * 16 + m16];
        oacc[g] = (f32x4){bias, bias, bias, bias};
    }
#pragma unroll
    for (int ks = 0; ks < 2; ++ks) {
        const int rowa = mf * 16 + m16;
        const float4 fA = *(const float4*)&t2s[rowa * 68 + ks * 32 + quad * 8];
        const float4 fB = *(const float4*)&t2s[rowa * 68 + ks * 32 + quad * 8 + 4];
        union { ushortT u[8]; bf16x8 v; } a_h, a_l;
        const float av[8] = {fA.x, fA.y, fA.z, fA.w, fB.x, fB.y, fB.z, fB.w};
#pragma unroll
        for (int e = 0; e < 8; ++e) split2(av[e], a_h.u[e], a_l.u[e]);
#pragma unroll
        for (int g = 0; g < 2; ++g) {
            const int rowc = (nh * 2 + g) * 16 + m16;
            const int cl = (ks * 4 + quad) ^ (rowc & 7);
            const bf16x8 b_h = *(const bf16x8*)&Wfh[rowc * 64 + cl * 8];
            const bf16x8 b_l = *(const bf16x8*)&Wfl[rowc * 64 + cl * 8];
            oacc[g] = __builtin_amdgcn_mfma_f32_16x16x32_bf16(a_h.v, b_h, oacc[g], 0, 0, 0);
            oacc[g] = __builtin_amdgcn_mfma_f32_16x16x32_bf16(a_h.v, b_l, oacc[g], 0, 0, 0);
            oacc[g] = __builtin_amdgcn_mfma_f32_16x16x32_bf16(a_l.v, b_h, oacc[g], 0, 0, 0);
        }
    }
#pragma unroll
    for (int g = 0; g < 2; ++g) {
        const int c = (nh * 2 + g) * 16 + m16;
#pragma unroll
        for (int reg = 0; reg < 4; ++reg) {
            const int i = i0 + mf * 16 + quad * 4 + reg;
            out[(size_t)(b * NN + i) * DOUT + c] = fmaxf(oacc[g][reg], 0.f);
        }
    }
}

extern "C" void kernel_launch(void* const* d_in, const int* in_sizes, int n_in,
                              void* d_out, int out_size, void* d_ws, size_t ws_size,
                              hipStream_t stream) {
    const float* x   = (const float*)d_in[0];
    const int*   adj = (const int*)d_in[1];
    const float* Wh  = (const float*)d_in[2];
    const float* ah  = (const float*)d_in[3];
    const float* Wo  = (const float*)d_in[4];
    const float* ao  = (const float*)d_in[5];
    const float* Wf  = (const float*)d_in[6];
    const float* bf  = (const float*)d_in[7];
    float* out = (float*)d_out;

    float* ws    = (float*)d_ws;
    float* src1  = ws;                                 // 4*8192
    float* dst1  = src1 + NH * RTOT;                   // 4*8192
    float* src2  = dst1 + NH * RTOT;                   // 8192
    float* dst2  = src2 + RTOT;                        // 8192
    ushortT* WhT   = (ushortT*)(dst2 + RTOT);                // 8192*512 bf16
    ushortT* Wh2T  = WhT + (size_t)RTOT * FCAT;              // 8192*64
    ushortT* xcat  = Wh2T + (size_t)RTOT * DOUT;             // 8192*512
    ushortT* WbTh  = xcat + (size_t)RTOT * FCAT;             // 131072
    ushortT* WbTl  = WbTh + NH * DH * DIN;
    ushortT* WoTh  = WbTl + NH * DH * DIN;                   // 32768
    ushortT* WoTl  = WoTh + DOUT * FCAT;
    unsigned* adjbit = (unsigned*)(WoTl + DOUT * FCAT);      // 262144 words

    hipLaunchKernelGGL(k_prepw, dim3((NH * DH * DIN + DOUT * FCAT) / 256), dim3(256), 0, stream,
                       Wh, Wo, WbTh, WbTl, WoTh, WoTl);
    hipLaunchKernelGGL(k_main,  dim3(768), dim3(512), 0, stream,
                       x, ah, WbTh, WbTl, adj, adjbit, WhT, src1, dst1);
    hipLaunchKernelGGL(k_attn1, dim3(1024), dim3(256), 0, stream,
                       adjbit, WhT, src1, dst1, xcat);
    hipLaunchKernelGGL(k_wh2,   dim3(256), dim3(256), 0, stream,
                       xcat, WoTh, WoTl, ao, Wh2T, src2, dst2);
    hipLaunchKernelGGL(k_attn2, dim3(256), dim3(256), 0, stream,
                       adjbit, Wh2T, src2, dst2, Wf, bf, out);
}

// Round 12
// 153.667 us; speedup vs baseline: 1.3454x; 1.0324x over previous
//
#include <hip/hip_runtime.h>
#include <hip/hip_bf16.h>

// Shapes (fixed by reference): B=8, N=1024, Din=256, H=4, Dh=128, Do=64
#define BSZ 8
#define NN 1024
#define DIN 256
#define NH 4
#define DH 128
#define DOUT 64
#define RTOT (BSZ*NN)          // 8192 rows total
#define FCAT (NH*DH)           // 512
#define ALPHA 0.2f

typedef unsigned short ushortT;
typedef __attribute__((ext_vector_type(8))) short bf16x8;
typedef __attribute__((ext_vector_type(4))) float f32x4;

static __device__ __forceinline__ ushortT f2bf(float f) {
    __hip_bfloat16 h = __float2bfloat16(f);
    return *reinterpret_cast<ushortT*>(&h);
}
static __device__ __forceinline__ float bfu2f(ushortT u) {
    return __uint_as_float(((unsigned)u) << 16);
}
static __device__ __forceinline__ void split2(float v, ushortT& hi, ushortT& lo) {
    hi = f2bf(v);
    lo = f2bf(v - bfu2f(hi));
}
// async global->LDS, 16B per lane; LDS dest = base(wave-uniform) + lane*16
static __device__ __forceinline__ void gload16(const ushortT* g, ushortT* l) {
    __builtin_amdgcn_global_load_lds(
        (const __attribute__((address_space(1))) unsigned int*)(const void*)g,
        (__attribute__((address_space(3))) unsigned int*)(void*)l, 16, 0, 0);
}

// ============ k_prepw: weight transforms only (bf16 hi/lo, k-contig) ============
__global__ __launch_bounds__(256) void k_prepw(const float* __restrict__ W,
                                               const float* __restrict__ Wout,
                                               ushortT* __restrict__ WbTh, ushortT* __restrict__ WbTl,
                                               ushortT* __restrict__ WoTh, ushortT* __restrict__ WoTl) {
    const int g2 = blockIdx.x * 256 + threadIdx.x;
    if (g2 < NH * DH * DIN) {           // 131072
        const int h = g2 >> 15, f = (g2 >> 8) & 127, k = g2 & 255;
        const int kt = k >> 6, k64 = k & 63;
        const float v = W[(size_t)h * DIN * DH + (size_t)k * DH + f];
        ushortT hi, lo; split2(v, hi, lo);
        const int idx = ((h * 4 + kt) * 128 + f) * 64 + k64;
        WbTh[idx] = hi; WbTl[idx] = lo;
    } else {
        const int g3 = g2 - NH * DH * DIN;   // < 32768
        const int f = g3 >> 9, k = g3 & 511;
        const float v = Wout[(size_t)k * DOUT + f];
        ushortT hi, lo; split2(v, hi, lo);
        WoTh[g3] = hi; WoTl[g3] = lo;
    }
}

// ============ k_main: blocks 0..255 = wh1 MFMA GEMM; blocks 256..767 = adj bit-pack ============
__global__ __launch_bounds__(512) void k_main(const float* __restrict__ x,
                                              const float* __restrict__ ah_,
                                              const ushortT* __restrict__ WbTh,
                                              const ushortT* __restrict__ WbTl,
                                              const int* __restrict__ adj,
                                              unsigned* __restrict__ adjbit,
                                              ushortT* __restrict__ WhT,
                                              float* __restrict__ src1,
                                              float* __restrict__ dst1) {
    __shared__ ushortT Ah[128 * 64], Al[128 * 64];    // 32 KB
    __shared__ ushortT Bh[128 * 64], Bl[128 * 64];    // 32 KB
    __shared__ float sred[8][32], dred[8][32];
    const int tid = threadIdx.x;
    if (blockIdx.x >= 256) {
        const int g = (blockIdx.x - 256) * 512 + tid;     // 262144 words
        const int row = g >> 5, w = g & 31;
        const int4* p = (const int4*)(adj + (size_t)row * NN + w * 32);
        unsigned m = 0;
#pragma unroll
        for (int q = 0; q < 8; ++q) {
            const int4 v = p[q];
            m |= (v.x > 0 ? 1u : 0u) << (q * 4 + 0);
            m |= (v.y > 0 ? 1u : 0u) << (q * 4 + 1);
            m |= (v.z > 0 ? 1u : 0u) << (q * 4 + 2);
            m |= (v.w > 0 ? 1u : 0u) << (q * 4 + 3);
        }
        adjbit[g] = m;
        return;
    }
    const int lane = tid & 63, wave = tid >> 6;
    const int h = blockIdx.x >> 6, mt = blockIdx.x & 63;
    const int r0 = mt * 128, b = r0 >> 10, jr = r0 & 1023;
    const int m16 = lane & 15, quad = lane >> 4;
    const int mg = wave >> 1, fg = wave & 1;
    const int arow = tid >> 2, apart = tid & 3;
    f32x4 acc[2][4];
#pragma unroll
    for (int a = 0; a < 2; ++a)
#pragma unroll
        for (int c = 0; c < 4; ++c) acc[a][c] = (f32x4){0.f, 0.f, 0.f, 0.f};

    for (int kt = 0; kt < 4; ++kt) {
        __syncthreads();
        const ushortT* planeH = WbTh + (size_t)((h * 4 + kt) * 128) * 64;
        const ushortT* planeL = WbTl + (size_t)((h * 4 + kt) * 128) * 64;
#pragma unroll
        for (int half = 0; half < 2; ++half) {
            const int f = wave * 16 + half * 8 + (lane >> 3);
            const int sc = (lane & 7) ^ (f & 7);
            gload16(planeH + (size_t)f * 64 + sc * 8, Bh + (wave * 16 + half * 8) * 64);
            gload16(planeL + (size_t)f * 64 + sc * 8, Bl + (wave * 16 + half * 8) * 64);
        }
        {
            const float4* xs = (const float4*)(x + (size_t)(r0 + arow) * DIN + kt * 64 + apart * 16);
            union { ushortT u[16]; uint4 q[2]; } th, tl;
#pragma unroll
            for (int e = 0; e < 4; ++e) {
                const float4 v = xs[e];
                split2(v.x, th.u[e * 4 + 0], tl.u[e * 4 + 0]);
                split2(v.y, th.u[e * 4 + 1], tl.u[e * 4 + 1]);
                split2(v.z, th.u[e * 4 + 2], tl.u[e * 4 + 2]);
                split2(v.w, th.u[e * 4 + 3], tl.u[e * 4 + 3]);
            }
            const int s0 = (2 * apart) ^ (arow & 7), s1 = (2 * apart + 1) ^ (arow & 7);
            *(uint4*)&Ah[arow * 64 + s0 * 8] = th.q[0];
            *(uint4*)&Ah[arow * 64 + s1 * 8] = th.q[1];
            *(uint4*)&Al[arow * 64 + s0 * 8] = tl.q[0];
            *(uint4*)&Al[arow * 64 + s1 * 8] = tl.q[1];
        }
        __syncthreads();
#pragma unroll
        for (int ks = 0; ks < 2; ++ks) {
            bf16x8 a_h[2], a_l[2], b_h[4], b_l[4];
#pragma unroll
            for (int ms = 0; ms < 2; ++ms) {
                const int row = (mg * 2 + ms) * 16 + m16;
                const int cl = (ks * 4 + quad) ^ (row & 7);
                a_h[ms] = *(const bf16x8*)&Ah[row * 64 + cl * 8];
                a_l[ms] = *(const bf16x8*)&Al[row * 64 + cl * 8];
            }
#pragma unroll
            for (int fs = 0; fs < 4; ++fs) {
                const int row = (fg * 4 + fs) * 16 + m16;
                const int cl = (ks * 4 + quad) ^ (row & 7);
                b_h[fs] = *(const bf16x8*)&Bh[row * 64 + cl * 8];
                b_l[fs] = *(const bf16x8*)&Bl[row * 64 + cl * 8];
            }
#pragma unroll
            for (int ms = 0; ms < 2; ++ms)
#pragma unroll
                for (int fs = 0; fs < 4; ++fs) {
                    acc[ms][fs] = __builtin_amdgcn_mfma_f32_16x16x32_bf16(a_h[ms], b_h[fs], acc[ms][fs], 0, 0, 0);
                    acc[ms][fs] = __builtin_amdgcn_mfma_f32_16x16x32_bf16(a_h[ms], b_l[fs], acc[ms][fs], 0, 0, 0);
                    acc[ms][fs] = __builtin_amdgcn_mfma_f32_16x16x32_bf16(a_l[ms], b_h[fs], acc[ms][fs], 0, 0, 0);
                }
        }
    }
    float sacc[2][4] = {{0,0,0,0},{0,0,0,0}}, dacc[2][4] = {{0,0,0,0},{0,0,0,0}};
#pragma unroll
    for (int ms = 0; ms < 2; ++ms)
#pragma unroll
        for (int fs = 0; fs < 4; ++fs) {
            const int fl = (fg * 4 + fs) * 16 + m16;
            const float a_s = ah_[h * 2 * DH + fl];
            const float a_d = ah_[h * 2 * DH + DH + fl];
            union { ushortT u[4]; uint2 q; } tw;
#pragma unroll
            for (int reg = 0; reg < 4; ++reg) {
                const float v = acc[ms][fs][reg];
                sacc[ms][reg] += v * a_s;
                dacc[ms][reg] += v * a_d;
                tw.u[reg] = f2bf(v);
            }
            *(uint2*)(WhT + ((size_t)((b * NH + h) * DH + fl)) * NN + jr + (mg * 2 + ms) * 16 + quad * 4) = tw.q;
        }
#pragma unroll
    for (int ms = 0; ms < 2; ++ms) {
#pragma unroll
        for (int reg = 0; reg < 4; ++reg) {
            float s = sacc[ms][reg], d = dacc[ms][reg];
#pragma unroll
            for (int o = 8; o > 0; o >>= 1) {
                s += __shfl_xor(s, o, 64);
                d += __shfl_xor(d, o, 64);
            }
            if (m16 == 0) {
                sred[wave][ms * 16 + quad * 4 + reg] = s;
                dred[wave][ms * 16 + quad * 4 + reg] = d;
            }
        }
    }
    __syncthreads();
    if (tid < 128) {
        const int mgr = tid >> 5, idx = tid & 31;
        src1[h * RTOT + r0 + tid] = sred[mgr * 2][idx] + sred[mgr * 2 + 1][idx];
        dst1[h * RTOT + r0 + tid] = dred[mgr * 2][idx] + dred[mgr * 2 + 1][idx];
    }
}

// ============ k_attn1: fused single-pass softmax + PV GEMM (layer 1), LDS double-buffer ====
// grid 1024 (bh = bx&31, it = bx>>5), 256 thr (4 waves), tile M=32, F=128, K=1024 (16 kt).
// Single barrier per K-tile: stage tile kt+1 into buf^1 (async B + in-reg exp A) while MFMA
// consumes buf. Reads of buf finish before any wave passes the next barrier; buf is only
// overwritten two barriers later. LDS 48.3KB -> 3 blocks/CU (was 4) — betting overlap > occ.
__global__ __launch_bounds__(256) void k_attn1(const unsigned* __restrict__ adjbit,
                                               const ushortT* __restrict__ WhT,
                                               const float* __restrict__ src1,
                                               const float* __restrict__ dst1,
                                               ushortT* __restrict__ xcat) {
    __shared__ ushortT As[2][32 * 64];               // 8 KB
    __shared__ ushortT Bs[2][128 * 64];              // 32 KB
    __shared__ unsigned maskS[32 * 32];              // 4 KB
    __shared__ float dstv[NN];                       // 4 KB
    __shared__ float srcv[32], rowinv[32], red4[4];
    const int tid = threadIdx.x, lane = tid & 63, wave = tid >> 6;
    const int bh = blockIdx.x & 31, it = blockIdx.x >> 5;
    const int b = bh >> 2, h = bh & 3;
    const int i0 = it * 32;
    const int m16 = lane & 15, quad = lane >> 4;

    const unsigned* mbase = adjbit + (size_t)(b * NN + i0) * 32;
#pragma unroll
    for (int k2 = 0; k2 < 4; ++k2) maskS[tid + 256 * k2] = mbase[tid + 256 * k2];
    float lm = -INFINITY;
#pragma unroll
    for (int k2 = 0; k2 < 4; ++k2) {
        const float d = dst1[h * RTOT + b * NN + tid + 256 * k2];
        dstv[tid + 256 * k2] = d;
        lm = fmaxf(lm, d);
    }
    if (tid < 32) srcv[tid] = src1[h * RTOT + b * NN + i0 + tid];
#pragma unroll
    for (int o = 32; o > 0; o >>= 1) lm = fmaxf(lm, __shfl_xor(lm, o, 64));
    if (lane == 0) red4[wave] = lm;
    __syncthreads();
    const float dmax = fmaxf(fmaxf(red4[0], red4[1]), fmaxf(red4[2], red4[3]));

    const int arow = tid >> 3, apart = tid & 7;      // 32 rows x 8 parts
    const float si = srcv[arow];
    float mrow = si + dmax;
    mrow = mrow >= 0.f ? mrow : ALPHA * mrow;        // per-row max (monotone leaky)
    float fsum = 0.f;

    const ushortT* Bbase = WhT + (size_t)(bh * DH) * NN;
    f32x4 acc[2][2];
#pragma unroll
    for (int a = 0; a < 2; ++a)
#pragma unroll
        for (int c = 0; c < 2; ++c) acc[a][c] = (f32x4){0.f, 0.f, 0.f, 0.f};

    // ---- staging helper (kt tile -> buffer buf): async B loads first, then exp-A compute
#define STAGE_TILE(kt_, buf_)                                                              \
    {                                                                                      \
        const int kt__ = (kt_);                                                            \
        ushortT* bdst = &Bs[(buf_)][0];                                                    \
        _Pragma("unroll")                                                                  \
        for (int half = 0; half < 4; ++half) {                                             \
            const int f = wave * 32 + half * 8 + (lane >> 3);                              \
            gload16(Bbase + (size_t)f * NN + kt__ * 64 + (((lane & 7) ^ (f & 7)) * 8),     \
                    bdst + (wave * 32 + half * 8) * 64);                                   \
        }                                                                                  \
        const unsigned w0 = maskS[arow * 32 + kt__ * 2 + (apart >> 2)];                    \
        const int bb = (apart & 3) * 8;                                                    \
        union { ushortT u[8]; uint4 q; } tw;                                               \
        _Pragma("unroll")                                                                  \
        for (int e4 = 0; e4 < 2; ++e4) {                                                   \
            const float4 dv = *(const float4*)&dstv[kt__ * 64 + apart * 8 + e4 * 4];       \
            const float vv[4] = {dv.x, dv.y, dv.z, dv.w};                                  \
            _Pragma("unroll")                                                              \
            for (int e = 0; e < 4; ++e) {                                                  \
                float v = si + vv[e];                                                      \
                v = v >= 0.f ? v : ALPHA * v;                                              \
                const unsigned bit = (w0 >> (bb + e4 * 4 + e)) & 1u;                       \
                const float p = bit ? __expf(v - mrow) : 0.f;                              \
                fsum += p;                                                                 \
                tw.u[e4 * 4 + e] = f2bf(p);                                                \
            }                                                                              \
        }                                                                                  \
        *(uint4*)&As[(buf_)][arow * 64 + (apart ^ (arow & 7)) * 8] = tw.q;                 \
    }

    STAGE_TILE(0, 0);                                // prologue
    for (int kt = 0; kt < 16; ++kt) {
        const int cb = kt & 1;
        __syncthreads();                             // buf cb writes visible; prior reads done
        if (kt < 15) STAGE_TILE(kt + 1, cb ^ 1);     // stage next while MFMA consumes current
#pragma unroll
        for (int ks = 0; ks < 2; ++ks) {
            bf16x8 afr[2];
#pragma unroll
            for (int ms = 0; ms < 2; ++ms) {
                const int rowa = ms * 16 + m16;
                const int cla = (ks * 4 + quad) ^ (rowa & 7);
                afr[ms] = *(const bf16x8*)&As[cb][rowa * 64 + cla * 8];
            }
#pragma unroll
            for (int ff = 0; ff < 2; ++ff) {
                const int rowb = wave * 32 + ff * 16 + m16;
                const int clb = (ks * 4 + quad) ^ (rowb & 7);
                const bf16x8 bfr = *(const bf16x8*)&Bs[cb][rowb * 64 + clb * 8];
#pragma unroll
                for (int ms = 0; ms < 2; ++ms)
                    acc[ms][ff] = __builtin_amdgcn_mfma_f32_16x16x32_bf16(afr[ms], bfr, acc[ms][ff], 0, 0, 0);
            }
        }
    }
#undef STAGE_TILE
#pragma unroll
    for (int o = 1; o < 8; o <<= 1) fsum += __shfl_xor(fsum, o, 64);
    if ((lane & 7) == 0) rowinv[arow] = 1.f / fsum;
    __syncthreads();
#pragma unroll
    for (int ms = 0; ms < 2; ++ms) {
        float rv[4];
#pragma unroll
        for (int reg = 0; reg < 4; ++reg) rv[reg] = rowinv[ms * 16 + quad * 4 + reg];
#pragma unroll
        for (int ff = 0; ff < 2; ++ff) {
            const int f = h * DH + wave * 32 + ff * 16 + m16;
#pragma unroll
            for (int reg = 0; reg < 4; ++reg) {
                const int i = i0 + ms * 16 + quad * 4 + reg;
                xcat[(size_t)(b * NN + i) * FCAT + f] = f2bf(acc[ms][ff][reg] * rv[reg]);
            }
        }
    }
}

// ============ k_wh2: Wh2 = xcat @ W_out, staged GEMM, fused Wh2T + src2/dst2 ============
// grid 256 (r0 = bx*32), 256 thr (4 waves), tile M=32, F=64, K=512 (8 kt)
__global__ __launch_bounds__(256) void k_wh2(const ushortT* __restrict__ xcat,
                                             const ushortT* __restrict__ WoTh,
                                             const ushortT* __restrict__ WoTl,
                                             const float* __restrict__ aout,
                                             ushortT* __restrict__ Wh2T,
                                             float* __restrict__ src2,
                                             float* __restrict__ dst2) {
    __shared__ ushortT As[32 * 64];                  // 4 KB
    __shared__ ushortT Bh[64 * 64], Bl[64 * 64];     // 16 KB
    __shared__ float sred[4][16], dred[4][16];
    const int tid = threadIdx.x, lane = tid & 63, wave = tid >> 6;
    const int r0 = blockIdx.x * 32;
    const int b = r0 >> 10, jr = r0 & 1023;
    const int m16 = lane & 15, quad = lane >> 4;
    const int mg = wave >> 1, fg = wave & 1;         // mg: row-frag 0..1, fg: f-half 0..1
    f32x4 acc[2] = {(f32x4){0.f,0.f,0.f,0.f}, (f32x4){0.f,0.f,0.f,0.f}};

    for (int kt = 0; kt < 8; ++kt) {
        __syncthreads();
        {   // A: 32 rows of xcat, wave covers 8 rows
            const int row = wave * 8 + (lane >> 3);
            const int sc = (lane & 7) ^ (row & 7);
            gload16(xcat + (size_t)(r0 + row) * FCAT + kt * 64 + sc * 8, As + wave * 8 * 64);
        }
#pragma unroll
        for (int half = 0; half < 2; ++half) {   // B: 64 f-rows, wave covers 16
            const int f = wave * 16 + half * 8 + (lane >> 3);
            const int sc = (lane & 7) ^ (f & 7);
            gload16(WoTh + (size_t)f * FCAT + kt * 64 + sc * 8, Bh + (wave * 16 + half * 8) * 64);
            gload16(WoTl + (size_t)f * FCAT + kt * 64 + sc * 8, Bl + (wave * 16 + half * 8) * 64);
        }
        __syncthreads();
#pragma unroll
        for (int ks = 0; ks < 2; ++ks) {
            const int rowa = mg * 16 + m16;
            const int cla = (ks * 4 + quad) ^ (rowa & 7);
            const bf16x8 afr = *(const bf16x8*)&As[rowa * 64 + cla * 8];
#pragma unroll
            for (int ff = 0; ff < 2; ++ff) {
                const int rowb = fg * 32 + ff * 16 + m16;
                const int clb = (ks * 4 + quad) ^ (rowb & 7);
                const bf16x8 b_h = *(const bf16x8*)&Bh[rowb * 64 + clb * 8];
                const bf16x8 b_l = *(const bf16x8*)&Bl[rowb * 64 + clb * 8];
                acc[ff] = __builtin_amdgcn_mfma_f32_16x16x32_bf16(afr, b_h, acc[ff], 0, 0, 0);
                acc[ff] = __builtin_amdgcn_mfma_f32_16x16x32_bf16(afr, b_l, acc[ff], 0, 0, 0);
            }
        }
    }
    // epilogue: Wh2T bf16 + fused src2/dst2 partials
    float sv[4] = {0, 0, 0, 0}, dv[4] = {0, 0, 0, 0};
#pragma unroll
    for (int ff = 0; ff < 2; ++ff) {
        const int f = fg * 32 + ff * 16 + m16;
        const float a_s = aout[f], a_d = aout[DOUT + f];
        union { ushortT u[4]; uint2 q; } tw;
#pragma unroll
        for (int reg = 0; reg < 4; ++reg) {
            const float v = acc[ff][reg];
            sv[reg] += v * a_s;
            dv[reg] += v * a_d;
            tw.u[reg] = f2bf(v);
        }
        *(uint2*)(Wh2T + ((size_t)(b * DOUT + f)) * NN + jr + mg * 16 + quad * 4) = tw.q;
    }
#pragma unroll
    for (int reg = 0; reg < 4; ++reg) {
#pragma unroll
        for (int o = 8; o > 0; o >>= 1) {
            sv[reg] += __shfl_xor(sv[reg], o, 64);
            dv[reg] += __shfl_xor(dv[reg], o, 64);
        }
        if (m16 == 0) { sred[wave][quad * 4 + reg] = sv[reg]; dred[wave][quad * 4 + reg] = dv[reg]; }
    }
    __syncthreads();
    if (tid < 32) {
        const int mgr = tid >> 4, idx = tid & 15;
        src2[r0 + tid] = sred[mgr * 2][idx] + sred[mgr * 2 + 1][idx];
        dst2[r0 + tid] = dred[mgr * 2][idx] + dred[mgr * 2 + 1][idx];
    }
}

// ============ k_attn2: single-pass softmax + PV + ELU + FC + ReLU (layer 2) ============
// grid 256 (b = bx&7, it = bx>>3), 256 thr, tile M=32, F=64, K=1024 (16 kt)
__global__ __launch_bounds__(256) void k_attn2(const unsigned* __restrict__ adjbit,
                                               const ushortT* __restrict__ Wh2T,
                                               const float* __restrict__ src2,
                                               const float* __restrict__ dst2,
                                               const float* __restrict__ Wf,
                                               const float* __restrict__ bfv,
                                               float* __restrict__ out) {
    __shared__ ushortT As[32 * 64];                 // 4 KB
    __shared__ ushortT Bs[64 * 64];                 // 8 KB
    __shared__ unsigned maskS[32 * 32];             // 4 KB
    __shared__ float dstv[NN];                      // 4 KB
    __shared__ ushortT Wfh[64 * 64], Wfl[64 * 64];  // 16 KB
    __shared__ float t2s[32 * 68];                  // 8.5 KB
    __shared__ float srcv[32], rowinv[32], red4[4];
    const int tid = threadIdx.x, lane = tid & 63, wave = tid >> 6;
    const int b = blockIdx.x & 7, it = blockIdx.x >> 3;
    const int i0 = it * 32;
    const int m16 = lane & 15, quad = lane >> 4;

    const unsigned* mbase = adjbit + (size_t)(b * NN + i0) * 32;
#pragma unroll
    for (int k2 = 0; k2 < 4; ++k2) maskS[tid + 256 * k2] = mbase[tid + 256 * k2];
    float lm = -INFINITY;
#pragma unroll
    for (int k2 = 0; k2 < 4; ++k2) {
        const float d = dst2[b * NN + tid + 256 * k2];
        dstv[tid + 256 * k2] = d;
        lm = fmaxf(lm, d);
    }
    if (tid < 32) srcv[tid] = src2[b * NN + i0 + tid];
    {   // stage Wf as hi/lo, layout [c][k] swizzled
        const int c = tid & 63, kc = (tid >> 6) * 16;
        union { ushortT u[16]; uint4 q[2]; } th, tl;
#pragma unroll
        for (int e = 0; e < 16; ++e)
            split2(Wf[(size_t)(kc + e) * DOUT + c], th.u[e], tl.u[e]);
        const int s0 = ((tid >> 6) * 2) ^ (c & 7), s1 = ((tid >> 6) * 2 + 1) ^ (c & 7);
        *(uint4*)&Wfh[c * 64 + s0 * 8] = th.q[0];
        *(uint4*)&Wfh[c * 64 + s1 * 8] = th.q[1];
        *(uint4*)&Wfl[c * 64 + s0 * 8] = tl.q[0];
        *(uint4*)&Wfl[c * 64 + s1 * 8] = tl.q[1];
    }
#pragma unroll
    for (int o = 32; o > 0; o >>= 1) lm = fmaxf(lm, __shfl_xor(lm, o, 64));
    if (lane == 0) red4[wave] = lm;
    __syncthreads();
    const float dmax = fmaxf(fmaxf(red4[0], red4[1]), fmaxf(red4[2], red4[3]));

    const int arow = tid >> 3, apart = tid & 7;      // 32 rows x 8 parts
    const float si = srcv[arow];
    float mrow = si + dmax;
    mrow = mrow >= 0.f ? mrow : ALPHA * mrow;
    float fsum = 0.f;

    const int mfrag = wave >> 1, fh = wave & 1;
    const ushortT* Bbase = Wh2T + (size_t)(b * DOUT) * NN;
    f32x4 acc[2] = {(f32x4){0.f,0.f,0.f,0.f}, (f32x4){0.f,0.f,0.f,0.f}};

    for (int kt = 0; kt < 16; ++kt) {
        __syncthreads();
#pragma unroll
        for (int half = 0; half < 2; ++half) {
            const int f = wave * 16 + half * 8 + (lane >> 3);
            gload16(Bbase + (size_t)f * NN + kt * 64 + (((lane & 7) ^ (f & 7)) * 8),
                    Bs + (wave * 16 + half * 8) * 64);
        }
        {
            const unsigned w0 = maskS[arow * 32 + kt * 2 + (apart >> 2)];
            const int bb = (apart & 3) * 8;
            union { ushortT u[8]; uint4 q; } tw;
#pragma unroll
            for (int e4 = 0; e4 < 2; ++e4) {
                const float4 dv = *(const float4*)&dstv[kt * 64 + apart * 8 + e4 * 4];
                const float vv[4] = {dv.x, dv.y, dv.z, dv.w};
#pragma unroll
                for (int e = 0; e < 4; ++e) {
                    float v = si + vv[e];
                    v = v >= 0.f ? v : ALPHA * v;
                    const unsigned bit = (w0 >> (bb + e4 * 4 + e)) & 1u;
                    const float p = bit ? __expf(v - mrow) : 0.f;
                    fsum += p;
                    tw.u[e4 * 4 + e] = f2bf(p);
                }
            }
            *(uint4*)&As[arow * 64 + (apart ^ (arow & 7)) * 8] = tw.q;
        }
        __syncthreads();
#pragma unroll
        for (int ks = 0; ks < 2; ++ks) {
            const int rowa = mfrag * 16 + m16;
            const int cla = (ks * 4 + quad) ^ (rowa & 7);
            const bf16x8 afr = *(const bf16x8*)&As[rowa * 64 + cla * 8];
#pragma unroll
            for (int ff = 0; ff < 2; ++ff) {
                const int rowb = (fh * 2 + ff) * 16 + m16;
                const int clb = (ks * 4 + quad) ^ (rowb & 7);
                const bf16x8 bfr = *(const bf16x8*)&Bs[rowb * 64 + clb * 8];
                acc[ff] = __builtin_amdgcn_mfma_f32_16x16x32_bf16(afr, bfr, acc[ff], 0, 0, 0);
            }
        }
    }
#pragma unroll
    for (int o = 1; o < 8; o <<= 1) fsum += __shfl_xor(fsum, o, 64);
    if ((lane & 7) == 0) rowinv[arow] = 1.f / fsum;
    __syncthreads();
#pragma unroll
    for (int ff = 0; ff < 2; ++ff) {
#pragma unroll
        for (int reg = 0; reg < 4; ++reg) {
            const int row = mfrag * 16 + quad * 4 + reg;
            float v = acc[ff][reg] * rowinv[row];
            v = v > 0.f ? v : (__expf(v) - 1.f);
            t2s[row * 68 + (fh * 2 + ff) * 16 + m16] = v;
        }
    }
    __syncthreads();
    const int mf = wave >> 1, nh = wave & 1;
    f32x4 oacc[2];
#pragma unroll
    for (int g = 0; g < 2; ++g) {
        const float bias = bfv[(nh * 2 + g) * 16 + m16];
        oacc[g] = (f32x4){bias, bias, bias, bias};
    }
#pragma unroll
    for (int ks = 0; ks < 2; ++ks) {
        const int rowa = mf * 16 + m16;
        const float4 fA = *(const float4*)&t2s[rowa * 68 + ks * 32 + quad * 8];
        const float4 fB = *(const float4*)&t2s[rowa * 68 + ks * 32 + quad * 8 + 4];
        union { ushortT u[8]; bf16x8 v; } a_h, a_l;
        const float av[8] = {fA.x, fA.y, fA.z, fA.w, fB.x, fB.y, fB.z, fB.w};
#pragma unroll
        for (int e = 0; e < 8; ++e) split2(av[e], a_h.u[e], a_l.u[e]);
#pragma unroll
        for (int g = 0; g < 2; ++g) {
            const int rowc = (nh * 2 + g) * 16 + m16;
            const int cl = (ks * 4 + quad) ^ (rowc & 7);
            const bf16x8 b_h = *(const bf16x8*)&Wfh[rowc * 64 + cl * 8];
            const bf16x8 b_l = *(const bf16x8*)&Wfl[rowc * 64 + cl * 8];
            oacc[g] = __builtin_amdgcn_mfma_f32_16x16x32_bf16(a_h.v, b_h, oacc[g], 0, 0, 0);
            oacc[g] = __builtin_amdgcn_mfma_f32_16x16x32_bf16(a_h.v, b_l, oacc[g], 0, 0, 0);
            oacc[g] = __builtin_amdgcn_mfma_f32_16x16x32_bf16(a_l.v, b_h, oacc[g], 0, 0, 0);
        }
    }
#pragma unroll
    for (int g = 0; g < 2; ++g) {
        const int c = (nh * 2 + g) * 16 + m16;
#pragma unroll
        for (int reg = 0; reg < 4; ++reg) {
            const int i = i0 + mf * 16 + quad * 4 + reg;
            out[(size_t)(b * NN + i) * DOUT + c] = fmaxf(oacc[g][reg], 0.f);
        }
    }
}

extern "C" void kernel_launch(void* const* d_in, const int* in_sizes, int n_in,
                              void* d_out, int out_size, void* d_ws, size_t ws_size,
                              hipStream_t stream) {
    const float* x   = (const float*)d_in[0];
    const int*   adj = (const int*)d_in[1];
    const float* Wh  = (const float*)d_in[2];
    const float* ah  = (const float*)d_in[3];
    const float* Wo  = (const float*)d_in[4];
    const float* ao  = (const float*)d_in[5];
    const float* Wf  = (const float*)d_in[6];
    const float* bf  = (const float*)d_in[7];
    float* out = (float*)d_out;

    float* ws    = (float*)d_ws;
    float* src1  = ws;                                 // 4*8192
    float* dst1  = src1 + NH * RTOT;                   // 4*8192
    float* src2  = dst1 + NH * RTOT;                   // 8192
    float* dst2  = src2 + RTOT;                        // 8192
    ushortT* WhT   = (ushortT*)(dst2 + RTOT);                // 8192*512 bf16
    ushortT* Wh2T  = WhT + (size_t)RTOT * FCAT;              // 8192*64
    ushortT* xcat  = Wh2T + (size_t)RTOT * DOUT;             // 8192*512
    ushortT* WbTh  = xcat + (size_t)RTOT * FCAT;             // 131072
    ushortT* WbTl  = WbTh + NH * DH * DIN;
    ushortT* WoTh  = WbTl + NH * DH * DIN;                   // 32768
    ushortT* WoTl  = WoTh + DOUT * FCAT;
    unsigned* adjbit = (unsigned*)(WoTl + DOUT * FCAT);      // 262144 words

    hipLaunchKernelGGL(k_prepw, dim3((NH * DH * DIN + DOUT * FCAT) / 256), dim3(256), 0, stream,
                       Wh, Wo, WbTh, WbTl, WoTh, WoTl);
    hipLaunchKernelGGL(k_main,  dim3(768), dim3(512), 0, stream,
                       x, ah, WbTh, WbTl, adj, adjbit, WhT, src1, dst1);
    hipLaunchKernelGGL(k_attn1, dim3(1024), dim3(256), 0, stream,
                       adjbit, WhT, src1, dst1, xcat);
    hipLaunchKernelGGL(k_wh2,   dim3(256), dim3(256), 0, stream,
                       xcat, WoTh, WoTl, ao, Wh2T, src2, dst2);
    hipLaunchKernelGGL(k_attn2, dim3(256), dim3(256), 0, stream,
                       adjbit, Wh2T, src2, dst2, Wf, bf, out);
}